// Round 2
// baseline (989.432 us; speedup 1.0000x reference)
//
#include <hip/hip_runtime.h>

#define SEQ 2048
#define HID 4096
#define NH 32
#define NKV 8
#define HD 128
#define KVLD 2048  // KV buffer leading dim: cols [0,1024) = K, [1024,2048) = V

typedef __attribute__((ext_vector_type(8))) short short8;
typedef __attribute__((ext_vector_type(4))) float f32x4;

static __device__ __forceinline__ unsigned short f2bf(float f) {
  union { float f; unsigned u; } v; v.f = f;
  return (unsigned short)((v.u + 0x7fffu + ((v.u >> 16) & 1u)) >> 16);
}
static __device__ __forceinline__ float bf2f(unsigned short h) {
  union { unsigned u; float f; } v; v.u = ((unsigned)h) << 16;
  return v.f;
}

// ---------------- fp32 -> bf16 conversion (vectorized) ----------------
__global__ void cvt_bf16(const float* __restrict__ in, unsigned short* __restrict__ out, int n4) {
  int i = blockIdx.x * blockDim.x + threadIdx.x;
  int st = gridDim.x * blockDim.x;
  for (; i < n4; i += st) {
    float4 v = reinterpret_cast<const float4*>(in)[i];
    ushort4 o;
    o.x = f2bf(v.x); o.y = f2bf(v.y); o.z = f2bf(v.z); o.w = f2bf(v.w);
    reinterpret_cast<ushort4*>(out)[i] = o;
  }
}

// ---------------- RoPE cos/sin table ----------------
__global__ void rope_table(const int* __restrict__ pos, float* __restrict__ tab) {
  int t = blockIdx.x * blockDim.x + threadIdx.x;
  if (t >= SEQ * 64) return;
  int s = t >> 6, i = t & 63;
  float inv = powf(10000.0f, -(float)i / 64.0f);
  float ang = (float)pos[s] * inv;
  tab[s * 128 + i] = cosf(ang);
  tab[s * 128 + 64 + i] = sinf(ang);
}

// ---------------- RoPE apply, in place on bf16 Q and K (pair per thread) ----------------
__global__ void rope_apply(unsigned short* __restrict__ Q, unsigned short* __restrict__ KV,
                           const float* __restrict__ tab) {
  int t = blockIdx.x * blockDim.x + threadIdx.x;
  const int QP = SEQ * NH * 64, KP = SEQ * NKV * 64;
  unsigned short* p;
  int s, i;
  if (t < QP) {
    s = t / (NH * 64); int r = t % (NH * 64);
    p = Q + (long)s * HID + (r >> 6) * HD; i = r & 63;
  } else if (t < QP + KP) {
    int u = t - QP;
    s = u / (NKV * 64); int r = u % (NKV * 64);
    p = KV + (long)s * KVLD + (r >> 6) * HD; i = r & 63;
  } else return;
  float c = tab[s * 128 + i], sn = tab[s * 128 + 64 + i];
  float x1 = bf2f(p[i]), x2 = bf2f(p[i + 64]);
  p[i]      = f2bf(x1 * c - x2 * sn);
  p[i + 64] = f2bf(x2 * c + x1 * sn);
}

// ---------------- BT GEMM: C[M,N] = A[M,K] * B[N,K]^T  (m97 structure) ----------------
static __device__ __forceinline__ void gl16(const unsigned short* g, unsigned short* l) {
  __builtin_amdgcn_global_load_lds((const __attribute__((address_space(1))) unsigned int*)g,
                                   (__attribute__((address_space(3))) unsigned int*)l, 16, 0, 0);
}

template <int EPI>  // 0: bf16 store, 1: fp32 + residual
__global__ __launch_bounds__(256)
void gemm_bt(const unsigned short* __restrict__ A, const unsigned short* __restrict__ B,
             unsigned short* __restrict__ Cb, float* __restrict__ Cf,
             const float* __restrict__ Res, int N, int K) {
  __shared__ unsigned short As[128 * 32];
  __shared__ unsigned short Bs[128 * 32];
  const int t = threadIdx.x, lane = t & 63, w = t >> 6;
  const int wr = w >> 1, wc = w & 1;
  const int m0 = blockIdx.x * 128, n0 = blockIdx.y * 128;

  const unsigned short* ga0 = A + (long)(m0 + (t >> 2)) * K + (t & 3) * 8;
  const unsigned short* ga1 = ga0 + 64L * K;
  const unsigned short* gb0 = B + (long)(n0 + (t >> 2)) * K + (t & 3) * 8;
  const unsigned short* gb1 = gb0 + 64L * K;
  unsigned short* la0 = As + t * 8;
  unsigned short* la1 = As + 2048 + t * 8;
  unsigned short* lb0 = Bs + t * 8;
  unsigned short* lb1 = Bs + 2048 + t * 8;

  const int aoff = (wr * 64 + (lane & 15)) * 32 + (lane >> 4) * 8;
  const int boff = (wc * 64 + (lane & 15)) * 32 + (lane >> 4) * 8;

  f32x4 acc[4][4] = {};

  for (int k0 = 0; k0 < K; k0 += 32) {
    gl16(ga0 + k0, la0);
    gl16(ga1 + k0, la1);
    gl16(gb0 + k0, lb0);
    gl16(gb1 + k0, lb1);
    __syncthreads();  // drains vmcnt -> LDS tiles complete
    short8 af[4], bfr[4];
#pragma unroll
    for (int i = 0; i < 4; i++) {
      af[i]  = *reinterpret_cast<const short8*>(As + aoff + i * 16 * 32);
      bfr[i] = *reinterpret_cast<const short8*>(Bs + boff + i * 16 * 32);
    }
#pragma unroll
    for (int mi = 0; mi < 4; mi++)
#pragma unroll
      for (int ni = 0; ni < 4; ni++)
        acc[mi][ni] = __builtin_amdgcn_mfma_f32_16x16x32_bf16(af[mi], bfr[ni], acc[mi][ni], 0, 0, 0);
    __syncthreads();  // protect LDS before next stage
  }

  const int crow = m0 + wr * 64 + ((lane >> 4) << 2);
  const int ccol = n0 + wc * 64 + (lane & 15);
#pragma unroll
  for (int mi = 0; mi < 4; mi++)
#pragma unroll
    for (int ni = 0; ni < 4; ni++)
#pragma unroll
      for (int j = 0; j < 4; j++) {
        long idx = (long)(crow + mi * 16 + j) * N + ccol + ni * 16;
        if (EPI == 0) Cb[idx] = f2bf(acc[mi][ni][j]);
        else          Cf[idx] = acc[mi][ni][j] + Res[idx];
      }
}

// ---------------- Flash attention (causal, GQA 4:1) ----------------
// grid: (32 q-blocks of 64 rows, 32 heads); block: 256 thr = 4 waves x 16 q-rows
__global__ __launch_bounds__(256)
void attn(const unsigned short* __restrict__ Q, const unsigned short* __restrict__ KV,
          unsigned short* __restrict__ O) {
  const int qb = blockIdx.x, h = blockIdx.y, kvh = h >> 2;
  __shared__ unsigned short Kl[32 * 136];     // K tile, padded rows (bank conflicts)
  __shared__ unsigned short Vt[128 * 40];     // V tile transposed [d][k], padded
  __shared__ unsigned short Pl[4][16 * 40];   // per-wave P transpose buffer
  const int t = threadIdx.x, lane = t & 63, w = t >> 6;

  short8 qf[4];
  {
    const int qrow = qb * 64 + w * 16 + (lane & 15);
    const unsigned short* qp = Q + (long)qrow * HID + h * HD + (lane >> 4) * 8;
#pragma unroll
    for (int kf = 0; kf < 4; kf++) qf[kf] = *reinterpret_cast<const short8*>(qp + kf * 32);
  }

  f32x4 oacc[8] = {};
  float m_run[4], l_run[4];
#pragma unroll
  for (int j = 0; j < 4; j++) { m_run[j] = -3e38f; l_run[j] = 0.f; }

  const float sc  = 0.08838834764831845f;   // 1/sqrt(128)
  const float L2E = 1.4426950408889634f;
  const int ktiles = 2 * qb + 2;
  const int qrow_l = qb * 64 + w * 16 + ((lane >> 4) << 2);

  for (int kt = 0; kt < ktiles; kt++) {
    __syncthreads();  // previous iteration's LDS reads done
#pragma unroll
    for (int it = 0; it < 2; it++) {
      const int row = (t >> 4) + it * 16, c0 = (t & 15) * 8;
      const unsigned short* src = KV + (long)(kt * 32 + row) * KVLD + kvh * HD + c0;
      short8 k8 = *reinterpret_cast<const short8*>(src);
      *reinterpret_cast<short8*>(Kl + row * 136 + c0) = k8;
      short8 v8 = *reinterpret_cast<const short8*>(src + 1024);
#pragma unroll
      for (int jj = 0; jj < 8; jj++) Vt[(c0 + jj) * 40 + row] = (unsigned short)v8[jj];
    }
    __syncthreads();

    // S = Q K^T  (16 rows x 32 cols per wave)
    f32x4 sacc[2] = {};
#pragma unroll
    for (int nt = 0; nt < 2; nt++)
#pragma unroll
      for (int kf = 0; kf < 4; kf++) {
        short8 kfr = *reinterpret_cast<const short8*>(
            Kl + (nt * 16 + (lane & 15)) * 136 + kf * 32 + (lane >> 4) * 8);
        sacc[nt] = __builtin_amdgcn_mfma_f32_16x16x32_bf16(qf[kf], kfr, sacc[nt], 0, 0, 0);
      }

    // scale + causal mask + tile row-max
    const int kcol = kt * 32 + (lane & 15);
    float mt[4];
#pragma unroll
    for (int j = 0; j < 4; j++) {
#pragma unroll
      for (int nt = 0; nt < 2; nt++) {
        float s = sacc[nt][j] * sc;
        if (kcol + nt * 16 > qrow_l + j) s = -3e38f;
        sacc[nt][j] = s;
      }
      mt[j] = fmaxf(sacc[0][j], sacc[1][j]);
    }
#pragma unroll
    for (int d = 1; d < 16; d <<= 1)
#pragma unroll
      for (int j = 0; j < 4; j++) mt[j] = fmaxf(mt[j], __shfl_xor(mt[j], d));

    // online softmax update
    float rs[4], prow[4];
#pragma unroll
    for (int j = 0; j < 4; j++) {
      float mn = fmaxf(m_run[j], mt[j]);
      rs[j] = exp2f((m_run[j] - mn) * L2E);
      m_run[j] = mn;
      float p0 = exp2f((sacc[0][j] - mn) * L2E);
      float p1 = exp2f((sacc[1][j] - mn) * L2E);
      sacc[0][j] = p0; sacc[1][j] = p1;
      prow[j] = p0 + p1;
    }
#pragma unroll
    for (int d = 1; d < 16; d <<= 1)
#pragma unroll
      for (int j = 0; j < 4; j++) prow[j] += __shfl_xor(prow[j], d);
#pragma unroll
    for (int j = 0; j < 4; j++) l_run[j] = l_run[j] * rs[j] + prow[j];
#pragma unroll
    for (int n8 = 0; n8 < 8; n8++)
#pragma unroll
      for (int j = 0; j < 4; j++) oacc[n8][j] *= rs[j];

    // P (C-layout) -> LDS -> A-frag layout
    unsigned short* pw = &Pl[w][0];
#pragma unroll
    for (int j = 0; j < 4; j++) {
      int r = ((lane >> 4) << 2) + j;
      pw[r * 40 + (lane & 15)]      = f2bf(sacc[0][j]);
      pw[r * 40 + 16 + (lane & 15)] = f2bf(sacc[1][j]);
    }
    short8 pf = *reinterpret_cast<const short8*>(pw + (lane & 15) * 40 + (lane >> 4) * 8);

    // O += P V
#pragma unroll
    for (int n8 = 0; n8 < 8; n8++) {
      short8 vf = *reinterpret_cast<const short8*>(Vt + (n8 * 16 + (lane & 15)) * 40 + (lane >> 4) * 8);
      oacc[n8] = __builtin_amdgcn_mfma_f32_16x16x32_bf16(pf, vf, oacc[n8], 0, 0, 0);
    }
  }

  float inv[4];
#pragma unroll
  for (int j = 0; j < 4; j++) inv[j] = 1.0f / l_run[j];
  const int orow = qb * 64 + w * 16 + ((lane >> 4) << 2);
#pragma unroll
  for (int n8 = 0; n8 < 8; n8++)
#pragma unroll
    for (int j = 0; j < 4; j++)
      O[(long)(orow + j) * HID + h * HD + n8 * 16 + (lane & 15)] = f2bf(oacc[n8][j] * inv[j]);
}

// ---------------- launch ----------------
extern "C" void kernel_launch(void* const* d_in, const int* in_sizes, int n_in,
                              void* d_out, int out_size, void* d_ws, size_t ws_size,
                              hipStream_t stream) {
  const float* hs  = (const float*)d_in[0];
  const float* res = (const float*)d_in[1];
  const float* Wq  = (const float*)d_in[2];
  const float* Wk  = (const float*)d_in[3];
  const float* Wv  = (const float*)d_in[4];
  const float* Wo  = (const float*)d_in[5];
  const int* pos   = (const int*)d_in[7];   // int32! (jax x64 disabled)
  float* out = (float*)d_out;

  char* w = (char*)d_ws;
  unsigned short* hsb  = (unsigned short*)w; w += (size_t)SEQ * HID * 2;
  unsigned short* wqb  = (unsigned short*)w; w += (size_t)HID * HID * 2;
  unsigned short* wkvb = (unsigned short*)w; w += (size_t)KVLD * HID * 2;
  unsigned short* wob  = (unsigned short*)w; w += (size_t)HID * HID * 2;
  unsigned short* Qb   = (unsigned short*)w; w += (size_t)SEQ * HID * 2;
  unsigned short* KVb  = (unsigned short*)w; w += (size_t)SEQ * KVLD * 2;
  unsigned short* Ab   = (unsigned short*)w; w += (size_t)SEQ * HID * 2;
  float* tab           = (float*)w;          w += (size_t)SEQ * 128 * 4;

  cvt_bf16<<<2048, 256, 0, stream>>>(hs, hsb, SEQ * HID / 4);
  cvt_bf16<<<2048, 256, 0, stream>>>(Wq, wqb, HID * HID / 4);
  cvt_bf16<<<1024, 256, 0, stream>>>(Wk, wkvb, 1024 * HID / 4);
  cvt_bf16<<<1024, 256, 0, stream>>>(Wv, wkvb + 1024 * HID, 1024 * HID / 4);
  cvt_bf16<<<2048, 256, 0, stream>>>(Wo, wob, HID * HID / 4);
  rope_table<<<SEQ * 64 / 256, 256, 0, stream>>>(pos, tab);

  gemm_bt<0><<<dim3(16, 32), 256, 0, stream>>>(hsb, wqb,  Qb,  nullptr, nullptr, HID,  HID);
  gemm_bt<0><<<dim3(16, 16), 256, 0, stream>>>(hsb, wkvb, KVb, nullptr, nullptr, KVLD, HID);

  rope_apply<<<(SEQ * NH * 64 + SEQ * NKV * 64) / 256, 256, 0, stream>>>(Qb, KVb, tab);

  attn<<<dim3(32, 32), 256, 0, stream>>>(Qb, KVb, Ab);

  gemm_bt<1><<<dim3(16, 32), 256, 0, stream>>>(Ab, wob, nullptr, out, res, HID, HID);
}

// Round 3
// 661.160 us; speedup vs baseline: 1.4965x; 1.4965x over previous
//
#include <hip/hip_runtime.h>

#define SEQ 2048
#define HID 4096
#define NH 32
#define NKV 8
#define HD 128

typedef __attribute__((ext_vector_type(8))) short short8;
typedef __attribute__((ext_vector_type(4))) float f32x4;

static __device__ __forceinline__ unsigned short f2bf(float f) {
  union { float f; unsigned u; } v; v.f = f;
  return (unsigned short)((v.u + 0x7fffu + ((v.u >> 16) & 1u)) >> 16);
}
static __device__ __forceinline__ float bf2f(unsigned short h) {
  union { unsigned u; float f; } v; v.u = ((unsigned)h) << 16;
  return v.f;
}

// ---------------- fp32 -> bf16 conversion (vectorized) ----------------
__global__ void cvt_bf16(const float* __restrict__ in, unsigned short* __restrict__ out, int n4) {
  int i = blockIdx.x * blockDim.x + threadIdx.x;
  int st = gridDim.x * blockDim.x;
  for (; i < n4; i += st) {
    float4 v = reinterpret_cast<const float4*>(in)[i];
    ushort4 o;
    o.x = f2bf(v.x); o.y = f2bf(v.y); o.z = f2bf(v.z); o.w = f2bf(v.w);
    reinterpret_cast<ushort4*>(out)[i] = o;
  }
}

// ---------------- RoPE cos/sin table ----------------
__global__ void rope_table(const int* __restrict__ pos, float* __restrict__ tab) {
  int t = blockIdx.x * blockDim.x + threadIdx.x;
  if (t >= SEQ * 64) return;
  int s = t >> 6, i = t & 63;
  float inv = powf(10000.0f, -(float)i / 64.0f);
  float ang = (float)pos[s] * inv;
  tab[s * 128 + i] = cosf(ang);
  tab[s * 128 + 64 + i] = sinf(ang);
}

// ---------------- RoPE apply, in place on bf16 Q [2048][4096] and K [2048][1024] ----------------
__global__ void rope_apply(unsigned short* __restrict__ Q, unsigned short* __restrict__ K,
                           const float* __restrict__ tab) {
  int t = blockIdx.x * blockDim.x + threadIdx.x;
  const int QP = SEQ * NH * 64, KP = SEQ * NKV * 64;
  unsigned short* p;
  int s, i;
  if (t < QP) {
    s = t / (NH * 64); int r = t % (NH * 64);
    p = Q + (long)s * HID + (r >> 6) * HD; i = r & 63;
  } else if (t < QP + KP) {
    int u = t - QP;
    s = u / (NKV * 64); int r = u % (NKV * 64);
    p = K + (long)s * 1024 + (r >> 6) * HD; i = r & 63;
  } else return;
  float c = tab[s * 128 + i], sn = tab[s * 128 + 64 + i];
  float x1 = bf2f(p[i]), x2 = bf2f(p[i + 64]);
  p[i]      = f2bf(x1 * c - x2 * sn);
  p[i + 64] = f2bf(x2 * c + x1 * sn);
}

// ---------------- BT GEMM: C[M,N] = A[M,K] * B[N,K]^T  (m97 structure) ----------------
static __device__ __forceinline__ void gl16(const unsigned short* g, unsigned short* l) {
  __builtin_amdgcn_global_load_lds((const __attribute__((address_space(1))) unsigned int*)g,
                                   (__attribute__((address_space(3))) unsigned int*)l, 16, 0, 0);
}

// EPI 0: bf16 store to Cb (LD=N)
// EPI 1: fp32 + residual to Cf (LD=N)
// EPI 2: KV split — blockIdx.y<8: K bf16 to Cb LD=1024; else V^T to Vt [8][128][2048]
template <int EPI>
__global__ __launch_bounds__(256)
void gemm_bt(const unsigned short* __restrict__ A, const unsigned short* __restrict__ B,
             unsigned short* __restrict__ Cb, float* __restrict__ Cf,
             const float* __restrict__ Res, unsigned short* __restrict__ Vt, int N, int K) {
  __shared__ unsigned short As[128 * 32];
  __shared__ unsigned short Bs[128 * 32];
  const int t = threadIdx.x, lane = t & 63, w = t >> 6;
  const int wr = w >> 1, wc = w & 1;
  const int m0 = blockIdx.x * 128, n0 = blockIdx.y * 128;

  const unsigned short* ga0 = A + (long)(m0 + (t >> 2)) * K + (t & 3) * 8;
  const unsigned short* ga1 = ga0 + 64L * K;
  const unsigned short* gb0 = B + (long)(n0 + (t >> 2)) * K + (t & 3) * 8;
  const unsigned short* gb1 = gb0 + 64L * K;
  unsigned short* la0 = As + t * 8;
  unsigned short* la1 = As + 2048 + t * 8;
  unsigned short* lb0 = Bs + t * 8;
  unsigned short* lb1 = Bs + 2048 + t * 8;

  const int aoff = (wr * 64 + (lane & 15)) * 32 + (lane >> 4) * 8;
  const int boff = (wc * 64 + (lane & 15)) * 32 + (lane >> 4) * 8;

  f32x4 acc[4][4] = {};

  for (int k0 = 0; k0 < K; k0 += 32) {
    gl16(ga0 + k0, la0);
    gl16(ga1 + k0, la1);
    gl16(gb0 + k0, lb0);
    gl16(gb1 + k0, lb1);
    __syncthreads();
    short8 af[4], bfr[4];
#pragma unroll
    for (int i = 0; i < 4; i++) {
      af[i]  = *reinterpret_cast<const short8*>(As + aoff + i * 16 * 32);
      bfr[i] = *reinterpret_cast<const short8*>(Bs + boff + i * 16 * 32);
    }
#pragma unroll
    for (int mi = 0; mi < 4; mi++)
#pragma unroll
      for (int ni = 0; ni < 4; ni++)
        acc[mi][ni] = __builtin_amdgcn_mfma_f32_16x16x32_bf16(af[mi], bfr[ni], acc[mi][ni], 0, 0, 0);
    __syncthreads();
  }

  const int crow = m0 + wr * 64 + ((lane >> 4) << 2);
  const int ccol = n0 + wc * 64 + (lane & 15);
  if (EPI == 2 && blockIdx.y >= 8) {
    // V^T: rows of C (kv) become the fast dim -> ushort4 packed stores
#pragma unroll
    for (int mi = 0; mi < 4; mi++)
#pragma unroll
      for (int ni = 0; ni < 4; ni++) {
        int c = ccol + ni * 16 - 1024;
        int head = c >> 7, d = c & 127;
        ushort4 pk;
        pk.x = f2bf(acc[mi][ni][0]); pk.y = f2bf(acc[mi][ni][1]);
        pk.z = f2bf(acc[mi][ni][2]); pk.w = f2bf(acc[mi][ni][3]);
        *reinterpret_cast<ushort4*>(Vt + ((size_t)head * 128 + d) * 2048 + crow + mi * 16) = pk;
      }
    return;
  }
#pragma unroll
  for (int mi = 0; mi < 4; mi++)
#pragma unroll
    for (int ni = 0; ni < 4; ni++)
#pragma unroll
      for (int j = 0; j < 4; j++) {
        if (EPI == 1) {
          long idx = (long)(crow + mi * 16 + j) * N + ccol + ni * 16;
          Cf[idx] = acc[mi][ni][j] + Res[idx];
        } else if (EPI == 2) {
          Cb[(long)(crow + mi * 16 + j) * 1024 + ccol + ni * 16] = f2bf(acc[mi][ni][j]);
        } else {
          Cb[(long)(crow + mi * 16 + j) * N + ccol + ni * 16] = f2bf(acc[mi][ni][j]);
        }
      }
}

// ---------------- Flash attention (causal, GQA 4:1) ----------------
// grid: (32 heads, 32 q-blocks); block 256 = 4 waves x 16 q-rows. KVBLK=64.
// K global [2048][1024] (head-major cols), V^T global [8][128][2048].
__global__ __launch_bounds__(256)
void attn(const unsigned short* __restrict__ Q, const unsigned short* __restrict__ Kg,
          const unsigned short* __restrict__ Vg, unsigned short* __restrict__ O) {
  const int h = blockIdx.x, qb = 31 - blockIdx.y, kvh = h >> 2;
  __shared__ unsigned short Kl[64 * 128];   // swizzled rows of 256B
  __shared__ unsigned short Vl[128 * 64];   // V^T tile, swizzled rows of 128B
  __shared__ unsigned short Pl[4][16 * 72]; // per-wave P buffer
  const int t = threadIdx.x, lane = t & 63, w = t >> 6, g = lane >> 4;

  short8 qf[4];
  {
    const int qrow = qb * 64 + w * 16 + (lane & 15);
    const unsigned short* qp = Q + (size_t)qrow * HID + h * HD + g * 8;
#pragma unroll
    for (int kf = 0; kf < 4; kf++) qf[kf] = *reinterpret_cast<const short8*>(qp + kf * 32);
  }

  f32x4 oacc[8] = {};
  float m_run[4], l_run[4];
#pragma unroll
  for (int j = 0; j < 4; j++) { m_run[j] = -3e38f; l_run[j] = 0.f; }

  const float SCL2E = 0.08838834764831845f * 1.4426950408889634f;
  const int ktiles = qb + 1;
  const int qrow_l = qb * 64 + w * 16 + g * 4;

  const unsigned short* kbase = Kg + kvh * HD;
  const unsigned short* vbase = Vg + (size_t)kvh * 128 * 2048;

  // staging regs: 4 K slots (row=slot>>4, cs=slot&15), 4 V slots (row=slot>>3, cs=slot&7)
  short8 kreg[4], vreg[4];
#define LOADKV(KT)                                                                     \
  {                                                                                    \
    _Pragma("unroll") for (int i = 0; i < 4; i++) {                                    \
      int slot = t + i * 256;                                                          \
      kreg[i] = *reinterpret_cast<const short8*>(                                      \
          kbase + (size_t)((KT) * 64 + (slot >> 4)) * 1024 + (slot & 15) * 8);         \
      vreg[i] = *reinterpret_cast<const short8*>(                                      \
          vbase + (size_t)(slot >> 3) * 2048 + (KT) * 64 + (slot & 7) * 8);            \
    }                                                                                  \
  }

  LOADKV(0);

  for (int kt = 0; kt < ktiles; kt++) {
    __syncthreads();  // prior tile's LDS reads complete
#pragma unroll
    for (int i = 0; i < 4; i++) {
      int slot = t + i * 256;
      int kr = slot >> 4, kc = slot & 15;
      *reinterpret_cast<short8*>(Kl + kr * 128 + ((((kc * 16) ^ ((kr & 7) << 4))) >> 1)) = kreg[i];
      int vr = slot >> 3, vc = slot & 7;
      *reinterpret_cast<short8*>(Vl + vr * 64 + ((((vc * 16) ^ ((vr & 7) << 4))) >> 1)) = vreg[i];
    }
    __syncthreads();

    if (kt + 1 < ktiles) LOADKV(kt + 1);  // overlap next-tile global loads with compute

    // ---- S = Q K^T : 16 q x 64 kv per wave ----
    f32x4 sacc[4] = {};
#pragma unroll
    for (int nt = 0; nt < 4; nt++) {
      int row = nt * 16 + (lane & 15);
#pragma unroll
      for (int kf = 0; kf < 4; kf++) {
        short8 kfr = *reinterpret_cast<const short8*>(
            Kl + row * 128 + (((kf * 64 + g * 16) ^ ((row & 7) << 4)) >> 1));
        sacc[nt] = __builtin_amdgcn_mfma_f32_16x16x32_bf16(qf[kf], kfr, sacc[nt], 0, 0, 0);
      }
    }

    // ---- softmax (raw units; scale folded into exp2) ----
    float mt[4];
    if (kt == qb) {  // diagonal tile: causal mask
      const int kc0 = kt * 64 + (lane & 15);
#pragma unroll
      for (int j = 0; j < 4; j++)
#pragma unroll
        for (int nt = 0; nt < 4; nt++)
          if (kc0 + nt * 16 > qrow_l + j) sacc[nt][j] = -3e38f;
    }
#pragma unroll
    for (int j = 0; j < 4; j++)
      mt[j] = fmaxf(fmaxf(sacc[0][j], sacc[1][j]), fmaxf(sacc[2][j], sacc[3][j]));
#pragma unroll
    for (int d = 1; d < 16; d <<= 1)
#pragma unroll
      for (int j = 0; j < 4; j++) mt[j] = fmaxf(mt[j], __shfl_xor(mt[j], d));

    float rs[4], prow[4];
#pragma unroll
    for (int j = 0; j < 4; j++) {
      float mn = fmaxf(m_run[j], mt[j]);
      rs[j] = exp2f((m_run[j] - mn) * SCL2E);
      m_run[j] = mn;
      float mnl = mn * SCL2E;
      float p0 = exp2f(sacc[0][j] * SCL2E - mnl);
      float p1 = exp2f(sacc[1][j] * SCL2E - mnl);
      float p2 = exp2f(sacc[2][j] * SCL2E - mnl);
      float p3 = exp2f(sacc[3][j] * SCL2E - mnl);
      sacc[0][j] = p0; sacc[1][j] = p1; sacc[2][j] = p2; sacc[3][j] = p3;
      prow[j] = (p0 + p1) + (p2 + p3);
    }
#pragma unroll
    for (int d = 1; d < 16; d <<= 1)
#pragma unroll
      for (int j = 0; j < 4; j++) prow[j] += __shfl_xor(prow[j], d);
#pragma unroll
    for (int j = 0; j < 4; j++) l_run[j] = l_run[j] * rs[j] + prow[j];
#pragma unroll
    for (int n8 = 0; n8 < 8; n8++)
#pragma unroll
      for (int j = 0; j < 4; j++) oacc[n8][j] *= rs[j];

    // ---- P -> per-wave LDS -> A-frag ----
    unsigned short* pw = &Pl[w][0];
#pragma unroll
    for (int j = 0; j < 4; j++) {
      int r = g * 4 + j;
#pragma unroll
      for (int nt = 0; nt < 4; nt++)
        pw[r * 72 + nt * 16 + (lane & 15)] = f2bf(sacc[nt][j]);
    }
    short8 pf0 = *reinterpret_cast<const short8*>(pw + (lane & 15) * 72 + g * 8);
    short8 pf1 = *reinterpret_cast<const short8*>(pw + (lane & 15) * 72 + 32 + g * 8);

    // ---- O += P V ----
#pragma unroll
    for (int n8 = 0; n8 < 8; n8++) {
      int row = n8 * 16 + (lane & 15);
      short8 vf0 = *reinterpret_cast<const short8*>(
          Vl + row * 64 + (((g * 16) ^ ((row & 7) << 4)) >> 1));
      oacc[n8] = __builtin_amdgcn_mfma_f32_16x16x32_bf16(pf0, vf0, oacc[n8], 0, 0, 0);
      short8 vf1 = *reinterpret_cast<const short8*>(
          Vl + row * 64 + (((64 + g * 16) ^ ((row & 7) << 4)) >> 1));
      oacc[n8] = __builtin_amdgcn_mfma_f32_16x16x32_bf16(pf1, vf1, oacc[n8], 0, 0, 0);
    }
  }

  float inv[4];
#pragma unroll
  for (int j = 0; j < 4; j++) inv[j] = 1.0f / l_run[j];
  const int orow = qb * 64 + w * 16 + g * 4;
#pragma unroll
  for (int n8 = 0; n8 < 8; n8++)
#pragma unroll
    for (int j = 0; j < 4; j++)
      O[(size_t)(orow + j) * HID + h * HD + n8 * 16 + (lane & 15)] = f2bf(oacc[n8][j] * inv[j]);
#undef LOADKV
}

// ---------------- launch ----------------
extern "C" void kernel_launch(void* const* d_in, const int* in_sizes, int n_in,
                              void* d_out, int out_size, void* d_ws, size_t ws_size,
                              hipStream_t stream) {
  const float* hs  = (const float*)d_in[0];
  const float* res = (const float*)d_in[1];
  const float* Wq  = (const float*)d_in[2];
  const float* Wk  = (const float*)d_in[3];
  const float* Wv  = (const float*)d_in[4];
  const float* Wo  = (const float*)d_in[5];
  const int* pos   = (const int*)d_in[7];
  float* out = (float*)d_out;

  char* w = (char*)d_ws;
  unsigned short* hsb  = (unsigned short*)w; w += (size_t)SEQ * HID * 2;       // 16MB
  unsigned short* wqb  = (unsigned short*)w; w += (size_t)HID * HID * 2;       // 32MB
  unsigned short* wkvb = (unsigned short*)w; w += (size_t)2048 * HID * 2;      // 16MB
  unsigned short* wob  = (unsigned short*)w; w += (size_t)HID * HID * 2;       // 32MB
  unsigned short* Qb   = (unsigned short*)w; w += (size_t)SEQ * HID * 2;       // 16MB
  unsigned short* Kb   = (unsigned short*)w; w += (size_t)SEQ * 1024 * 2;      // 4MB
  unsigned short* Vtb  = (unsigned short*)w; w += (size_t)NKV * 128 * SEQ * 2; // 4MB
  unsigned short* Ab   = (unsigned short*)w; w += (size_t)SEQ * HID * 2;       // 16MB
  float* tab           = (float*)w;          w += (size_t)SEQ * 128 * 4;       // 1MB

  cvt_bf16<<<2048, 256, 0, stream>>>(hs, hsb, SEQ * HID / 4);
  cvt_bf16<<<2048, 256, 0, stream>>>(Wq, wqb, HID * HID / 4);
  cvt_bf16<<<1024, 256, 0, stream>>>(Wk, wkvb, 1024 * HID / 4);
  cvt_bf16<<<1024, 256, 0, stream>>>(Wv, wkvb + (size_t)1024 * HID, 1024 * HID / 4);
  cvt_bf16<<<2048, 256, 0, stream>>>(Wo, wob, HID * HID / 4);
  rope_table<<<SEQ * 64 / 256, 256, 0, stream>>>(pos, tab);

  gemm_bt<0><<<dim3(16, 32), 256, 0, stream>>>(hsb, wqb,  Qb, nullptr, nullptr, nullptr, HID, HID);
  gemm_bt<2><<<dim3(16, 16), 256, 0, stream>>>(hsb, wkvb, Kb, nullptr, nullptr, Vtb, 2048, HID);

  rope_apply<<<(SEQ * NH * 64 + SEQ * NKV * 64) / 256, 256, 0, stream>>>(Qb, Kb, tab);

  attn<<<dim3(32, 32), 256, 0, stream>>>(Qb, Kb, Vtb, Ab);

  gemm_bt<1><<<dim3(16, 32), 256, 0, stream>>>(Ab, wob, nullptr, out, res, nullptr, HID, HID);
}

// Round 4
// 625.981 us; speedup vs baseline: 1.5806x; 1.0562x over previous
//
#include <hip/hip_runtime.h>

#define SEQ 2048
#define HID 4096
#define NH 32
#define NKV 8
#define HD 128

typedef __attribute__((ext_vector_type(8))) short short8;
typedef __attribute__((ext_vector_type(4))) float f32x4;

#define CFENCE asm volatile("" ::: "memory")

static __device__ __forceinline__ unsigned short f2bf(float f) {
  union { float f; unsigned u; } v; v.f = f;
  return (unsigned short)((v.u + 0x7fffu + ((v.u >> 16) & 1u)) >> 16);
}
static __device__ __forceinline__ float bf2f(unsigned short h) {
  union { unsigned u; float f; } v; v.u = ((unsigned)h) << 16;
  return v.f;
}

// ---------------- fp32 -> bf16 conversion (vectorized) ----------------
__global__ void cvt_bf16(const float* __restrict__ in, unsigned short* __restrict__ out, int n4) {
  int i = blockIdx.x * blockDim.x + threadIdx.x;
  int st = gridDim.x * blockDim.x;
  for (; i < n4; i += st) {
    float4 v = reinterpret_cast<const float4*>(in)[i];
    ushort4 o;
    o.x = f2bf(v.x); o.y = f2bf(v.y); o.z = f2bf(v.z); o.w = f2bf(v.w);
    reinterpret_cast<ushort4*>(out)[i] = o;
  }
}

// ---------------- RoPE cos/sin table ----------------
__global__ void rope_table(const int* __restrict__ pos, float* __restrict__ tab) {
  int t = blockIdx.x * blockDim.x + threadIdx.x;
  if (t >= SEQ * 64) return;
  int s = t >> 6, i = t & 63;
  float inv = powf(10000.0f, -(float)i / 64.0f);
  float ang = (float)pos[s] * inv;
  tab[s * 128 + i] = cosf(ang);
  tab[s * 128 + 64 + i] = sinf(ang);
}

// ---------------- RoPE apply, in place on bf16 Q [2048][4096] and K [2048][1024] ----------------
__global__ void rope_apply(unsigned short* __restrict__ Q, unsigned short* __restrict__ K,
                           const float* __restrict__ tab) {
  int t = blockIdx.x * blockDim.x + threadIdx.x;
  const int QP = SEQ * NH * 64, KP = SEQ * NKV * 64;
  unsigned short* p;
  int s, i;
  if (t < QP) {
    s = t / (NH * 64); int r = t % (NH * 64);
    p = Q + (long)s * HID + (r >> 6) * HD; i = r & 63;
  } else if (t < QP + KP) {
    int u = t - QP;
    s = u / (NKV * 64); int r = u % (NKV * 64);
    p = K + (long)s * 1024 + (r >> 6) * HD; i = r & 63;
  } else return;
  float c = tab[s * 128 + i], sn = tab[s * 128 + 64 + i];
  float x1 = bf2f(p[i]), x2 = bf2f(p[i + 64]);
  p[i]      = f2bf(x1 * c - x2 * sn);
  p[i + 64] = f2bf(x2 * c + x1 * sn);
}

// ---------------- async global->LDS, 16B ----------------
static __device__ __forceinline__ void gl16(const unsigned short* g, unsigned short* l) {
  __builtin_amdgcn_global_load_lds((const __attribute__((address_space(1))) unsigned int*)g,
                                   (__attribute__((address_space(3))) unsigned int*)l, 16, 0, 0);
}

// Stage one 128x64 bf16 half-tile (16KB) with pre-swizzled global source so that
// LDS[row*64 + jc*8 .. +8] = G[row][ (jc ^ (row&7))*8 .. +8 ]  (involution swizzle).
// 512 threads x 2 chunks of 16B. gsrc already offset to (row0, k0).
static __device__ __forceinline__ void stage_half(const unsigned short* __restrict__ gsrc,
                                                  unsigned short* __restrict__ dst, int K, int t) {
#pragma unroll
  for (int p = 0; p < 2; p++) {
    int chunk = p * 512 + t;
    int row = chunk >> 3, j = chunk & 7;
    gl16(gsrc + (size_t)row * K + ((j ^ (row & 7)) << 3), dst + chunk * 8);
  }
}

// ======== 256x256 8-phase BT-GEMM: C[M,N] = A[M,K] * B[N,K]^T ========
// 512 threads = 8 waves (2M x 4N), per-wave C = 128x64, BK=64, LDS 128KB double-buffered.
// M fixed at 2048 (8 M-tiles). EPI 1: fp32 + residual. EPI 3: QKV split epilogue.
template <int EPI>
__global__ __launch_bounds__(512, 2)
void gemm256(const unsigned short* __restrict__ A, const unsigned short* __restrict__ B,
             unsigned short* __restrict__ Qo, unsigned short* __restrict__ Ko,
             unsigned short* __restrict__ Vt, float* __restrict__ Cf,
             const float* __restrict__ Res, int K) {
  __shared__ unsigned short smem[65536];  // 128 KiB: [buf0 A|buf0 B|buf1 A|buf1 B] x 32KB

  // bijective XCD swizzle (grid % 8 == 0): each XCD gets a contiguous chunk, M fast.
  const int nwg = gridDim.x, fid = blockIdx.x;
  const int sid = (fid & 7) * (nwg >> 3) + (fid >> 3);
  const int bm = sid & 7, bn = sid >> 3;

  const int t = threadIdx.x, lane = t & 63, w = t >> 6, g = lane >> 4;
  const int wm = w >> 2, wn = w & 3;

  const unsigned short* Abase = A + (size_t)(bm * 256) * K;
  const unsigned short* Bbase = B + (size_t)(bn * 256) * K;

  // prologue: stage K-tile 0 into buf0 (4 halves), full drain once
  stage_half(Abase,                  smem,         K, t);
  stage_half(Abase + (size_t)128 * K, smem + 8192,  K, t);
  stage_half(Bbase,                  smem + 16384, K, t);
  stage_half(Bbase + (size_t)128 * K, smem + 24576, K, t);
  asm volatile("s_waitcnt vmcnt(0)" ::: "memory");
  __syncthreads();

  f32x4 acc[8][4] = {};
  const int NT = K >> 6;

  for (int kt = 0; kt < NT; kt++) {
    const int buf = (kt & 1) << 15;       // elems
    const int nbuf = buf ^ 32768;
    const size_t knext = (size_t)(kt + 1) * 64;
    const bool prefetch = (kt + 1 < NT);
#pragma unroll
    for (int q = 0; q < 4; q++) {
      // --- ds_read quadrant fragments (12 x b128, swizzled) ---
      short8 af[4][2], bfv[2][2];
#pragma unroll
      for (int m2 = 0; m2 < 4; m2++) {
        const int rr = ((q >> 1) * 4 + m2) * 16 + (lane & 15);
        const unsigned short* pA = smem + buf + wm * 8192 + rr * 64;
#pragma unroll
        for (int ks = 0; ks < 2; ks++)
          af[m2][ks] = *reinterpret_cast<const short8*>(
              pA + ((ks * 32 + g * 8) ^ ((rr & 7) << 3)));
      }
#pragma unroll
      for (int n2 = 0; n2 < 2; n2++) {
        const int nl = wn * 64 + ((q & 1) * 2 + n2) * 16 + (lane & 15);
        const unsigned short* pB = smem + buf + 16384 + (nl >> 7) * 8192 + (nl & 127) * 64;
#pragma unroll
        for (int ks = 0; ks < 2; ks++)
          bfv[n2][ks] = *reinterpret_cast<const short8*>(
              pB + ((ks * 32 + g * 8) ^ ((nl & 7) << 3)));
      }
      // --- stage one half of next K-tile (2 x global_load_lds) ---
      if (prefetch) {
        if (q < 2) stage_half(Abase + (size_t)(q * 128) * K + knext, smem + nbuf + q * 8192, K, t);
        else       stage_half(Bbase + (size_t)((q - 2) * 128) * K + knext,
                              smem + nbuf + 16384 + (q - 2) * 8192, K, t);
      }
      __builtin_amdgcn_s_barrier();
      CFENCE;
      __builtin_amdgcn_s_setprio(1);
#pragma unroll
      for (int m2 = 0; m2 < 4; m2++)
#pragma unroll
        for (int n2 = 0; n2 < 2; n2++)
#pragma unroll
          for (int ks = 0; ks < 2; ks++)
            acc[(q >> 1) * 4 + m2][(q & 1) * 2 + n2] =
                __builtin_amdgcn_mfma_f32_16x16x32_bf16(af[m2][ks], bfv[n2][ks],
                    acc[(q >> 1) * 4 + m2][(q & 1) * 2 + n2], 0, 0, 0);
      __builtin_amdgcn_s_setprio(0);
      if (q == 3 && prefetch) asm volatile("s_waitcnt vmcnt(0)" ::: "memory");
      __builtin_amdgcn_s_barrier();
      CFENCE;
    }
  }

  // ---- epilogue ----
  const int r0 = bm * 256 + wm * 128 + g * 4;
  const int c0 = bn * 256 + wn * 64 + (lane & 15);
#pragma unroll
  for (int mi = 0; mi < 8; mi++)
#pragma unroll
    for (int ni = 0; ni < 4; ni++) {
      const int row = r0 + mi * 16;
      const int col = c0 + ni * 16;
      if (EPI == 1) {
#pragma unroll
        for (int j = 0; j < 4; j++) {
          size_t idx = (size_t)(row + j) * 4096 + col;
          Cf[idx] = acc[mi][ni][j] + Res[idx];
        }
      } else {
        if (col < 4096) {
#pragma unroll
          for (int j = 0; j < 4; j++)
            Qo[(size_t)(row + j) * 4096 + col] = f2bf(acc[mi][ni][j]);
        } else if (col < 5120) {
#pragma unroll
          for (int j = 0; j < 4; j++)
            Ko[(size_t)(row + j) * 1024 + (col - 4096)] = f2bf(acc[mi][ni][j]);
        } else {
          const int c = col - 5120;
          ushort4 pk;
          pk.x = f2bf(acc[mi][ni][0]); pk.y = f2bf(acc[mi][ni][1]);
          pk.z = f2bf(acc[mi][ni][2]); pk.w = f2bf(acc[mi][ni][3]);
          *reinterpret_cast<ushort4*>(
              Vt + ((size_t)((c >> 7) * 128 + (c & 127))) * 2048 + row) = pk;
        }
      }
    }
}

// ---------------- Flash attention (causal, GQA 4:1) ----------------
// grid: (32 heads, 32 q-blocks); block 256 = 4 waves x 16 q-rows. KVBLK=64.
// K global [2048][1024] (head-major cols), V^T global [8][128][2048].
__global__ __launch_bounds__(256)
void attn(const unsigned short* __restrict__ Q, const unsigned short* __restrict__ Kg,
          const unsigned short* __restrict__ Vg, unsigned short* __restrict__ O) {
  const int h = blockIdx.x, qb = 31 - blockIdx.y, kvh = h >> 2;
  __shared__ unsigned short Kl[64 * 128];   // swizzled rows of 256B
  __shared__ unsigned short Vl[128 * 64];   // V^T tile, swizzled rows of 128B
  __shared__ unsigned short Pl[4][16 * 72]; // per-wave P buffer
  const int t = threadIdx.x, lane = t & 63, w = t >> 6, g = lane >> 4;

  short8 qf[4];
  {
    const int qrow = qb * 64 + w * 16 + (lane & 15);
    const unsigned short* qp = Q + (size_t)qrow * HID + h * HD + g * 8;
#pragma unroll
    for (int kf = 0; kf < 4; kf++) qf[kf] = *reinterpret_cast<const short8*>(qp + kf * 32);
  }

  f32x4 oacc[8] = {};
  float m_run[4], l_run[4];
#pragma unroll
  for (int j = 0; j < 4; j++) { m_run[j] = -3e38f; l_run[j] = 0.f; }

  const float SCL2E = 0.08838834764831845f * 1.4426950408889634f;
  const int ktiles = qb + 1;
  const int qrow_l = qb * 64 + w * 16 + g * 4;

  const unsigned short* kbase = Kg + kvh * HD;
  const unsigned short* vbase = Vg + (size_t)kvh * 128 * 2048;

  short8 kreg[4], vreg[4];
#define LOADKV(KT)                                                                     \
  {                                                                                    \
    _Pragma("unroll") for (int i = 0; i < 4; i++) {                                    \
      int slot = t + i * 256;                                                          \
      kreg[i] = *reinterpret_cast<const short8*>(                                      \
          kbase + (size_t)((KT) * 64 + (slot >> 4)) * 1024 + (slot & 15) * 8);         \
      vreg[i] = *reinterpret_cast<const short8*>(                                      \
          vbase + (size_t)(slot >> 3) * 2048 + (KT) * 64 + (slot & 7) * 8);            \
    }                                                                                  \
  }

  LOADKV(0);

  for (int kt = 0; kt < ktiles; kt++) {
    __syncthreads();  // prior tile's LDS reads complete
#pragma unroll
    for (int i = 0; i < 4; i++) {
      int slot = t + i * 256;
      int kr = slot >> 4, kc = slot & 15;
      *reinterpret_cast<short8*>(Kl + kr * 128 + ((((kc * 16) ^ ((kr & 7) << 4))) >> 1)) = kreg[i];
      int vr = slot >> 3, vc = slot & 7;
      *reinterpret_cast<short8*>(Vl + vr * 64 + ((((vc * 16) ^ ((vr & 7) << 4))) >> 1)) = vreg[i];
    }
    __syncthreads();

    if (kt + 1 < ktiles) LOADKV(kt + 1);  // overlap next-tile global loads with compute

    // ---- S = Q K^T : 16 q x 64 kv per wave ----
    f32x4 sacc[4] = {};
#pragma unroll
    for (int nt = 0; nt < 4; nt++) {
      int row = nt * 16 + (lane & 15);
#pragma unroll
      for (int kf = 0; kf < 4; kf++) {
        short8 kfr = *reinterpret_cast<const short8*>(
            Kl + row * 128 + (((kf * 64 + g * 16) ^ ((row & 7) << 4)) >> 1));
        sacc[nt] = __builtin_amdgcn_mfma_f32_16x16x32_bf16(qf[kf], kfr, sacc[nt], 0, 0, 0);
      }
    }

    // ---- softmax (raw units; scale folded into exp2) ----
    float mt[4];
    if (kt == qb) {  // diagonal tile: causal mask
      const int kc0 = kt * 64 + (lane & 15);
#pragma unroll
      for (int j = 0; j < 4; j++)
#pragma unroll
        for (int nt = 0; nt < 4; nt++)
          if (kc0 + nt * 16 > qrow_l + j) sacc[nt][j] = -3e38f;
    }
#pragma unroll
    for (int j = 0; j < 4; j++)
      mt[j] = fmaxf(fmaxf(sacc[0][j], sacc[1][j]), fmaxf(sacc[2][j], sacc[3][j]));
#pragma unroll
    for (int d = 1; d < 16; d <<= 1)
#pragma unroll
      for (int j = 0; j < 4; j++) mt[j] = fmaxf(mt[j], __shfl_xor(mt[j], d));

    float rs[4], prow[4];
#pragma unroll
    for (int j = 0; j < 4; j++) {
      float mn = fmaxf(m_run[j], mt[j]);
      rs[j] = exp2f((m_run[j] - mn) * SCL2E);
      m_run[j] = mn;
      float mnl = mn * SCL2E;
      float p0 = exp2f(sacc[0][j] * SCL2E - mnl);
      float p1 = exp2f(sacc[1][j] * SCL2E - mnl);
      float p2 = exp2f(sacc[2][j] * SCL2E - mnl);
      float p3 = exp2f(sacc[3][j] * SCL2E - mnl);
      sacc[0][j] = p0; sacc[1][j] = p1; sacc[2][j] = p2; sacc[3][j] = p3;
      prow[j] = (p0 + p1) + (p2 + p3);
    }
#pragma unroll
    for (int d = 1; d < 16; d <<= 1)
#pragma unroll
      for (int j = 0; j < 4; j++) prow[j] += __shfl_xor(prow[j], d);
#pragma unroll
    for (int j = 0; j < 4; j++) l_run[j] = l_run[j] * rs[j] + prow[j];
#pragma unroll
    for (int n8 = 0; n8 < 8; n8++)
#pragma unroll
      for (int j = 0; j < 4; j++) oacc[n8][j] *= rs[j];

    // ---- P -> per-wave LDS -> A-frag ----
    unsigned short* pw = &Pl[w][0];
#pragma unroll
    for (int j = 0; j < 4; j++) {
      int r = g * 4 + j;
#pragma unroll
      for (int nt = 0; nt < 4; nt++)
        pw[r * 72 + nt * 16 + (lane & 15)] = f2bf(sacc[nt][j]);
    }
    short8 pf0 = *reinterpret_cast<const short8*>(pw + (lane & 15) * 72 + g * 8);
    short8 pf1 = *reinterpret_cast<const short8*>(pw + (lane & 15) * 72 + 32 + g * 8);

    // ---- O += P V ----
#pragma unroll
    for (int n8 = 0; n8 < 8; n8++) {
      int row = n8 * 16 + (lane & 15);
      short8 vf0 = *reinterpret_cast<const short8*>(
          Vl + row * 64 + (((g * 16) ^ ((row & 7) << 4)) >> 1));
      oacc[n8] = __builtin_amdgcn_mfma_f32_16x16x32_bf16(pf0, vf0, oacc[n8], 0, 0, 0);
      short8 vf1 = *reinterpret_cast<const short8*>(
          Vl + row * 64 + (((64 + g * 16) ^ ((row & 7) << 4)) >> 1));
      oacc[n8] = __builtin_amdgcn_mfma_f32_16x16x32_bf16(pf1, vf1, oacc[n8], 0, 0, 0);
    }
  }

  float inv[4];
#pragma unroll
  for (int j = 0; j < 4; j++) inv[j] = 1.0f / l_run[j];
  const int orow = qb * 64 + w * 16 + g * 4;
#pragma unroll
  for (int n8 = 0; n8 < 8; n8++)
#pragma unroll
    for (int j = 0; j < 4; j++)
      O[(size_t)(orow + j) * HID + h * HD + n8 * 16 + (lane & 15)] = f2bf(oacc[n8][j] * inv[j]);
#undef LOADKV
}

// ---------------- launch ----------------
extern "C" void kernel_launch(void* const* d_in, const int* in_sizes, int n_in,
                              void* d_out, int out_size, void* d_ws, size_t ws_size,
                              hipStream_t stream) {
  const float* hs  = (const float*)d_in[0];
  const float* res = (const float*)d_in[1];
  const float* Wq  = (const float*)d_in[2];
  const float* Wk  = (const float*)d_in[3];
  const float* Wv  = (const float*)d_in[4];
  const float* Wo  = (const float*)d_in[5];
  const int* pos   = (const int*)d_in[7];
  float* out = (float*)d_out;

  char* w = (char*)d_ws;
  unsigned short* hsb  = (unsigned short*)w; w += (size_t)SEQ * HID * 2;       // 16MB
  unsigned short* wqb  = (unsigned short*)w; w += (size_t)HID * HID * 2;       // 32MB  (rows 0-4095 of fused B)
  unsigned short* wkvb = (unsigned short*)w; w += (size_t)2048 * HID * 2;      // 16MB  (rows 4096-6143, contiguous!)
  unsigned short* wob  = (unsigned short*)w; w += (size_t)HID * HID * 2;       // 32MB
  unsigned short* Qb   = (unsigned short*)w; w += (size_t)SEQ * HID * 2;       // 16MB
  unsigned short* Kb   = (unsigned short*)w; w += (size_t)SEQ * 1024 * 2;      // 4MB
  unsigned short* Vtb  = (unsigned short*)w; w += (size_t)NKV * 128 * SEQ * 2; // 4MB
  unsigned short* Ab   = (unsigned short*)w; w += (size_t)SEQ * HID * 2;       // 16MB
  float* tab           = (float*)w;          w += (size_t)SEQ * 128 * 4;       // 1MB

  cvt_bf16<<<2048, 256, 0, stream>>>(hs, hsb, SEQ * HID / 4);
  cvt_bf16<<<2048, 256, 0, stream>>>(Wq, wqb, HID * HID / 4);
  cvt_bf16<<<1024, 256, 0, stream>>>(Wk, wkvb, 1024 * HID / 4);
  cvt_bf16<<<1024, 256, 0, stream>>>(Wv, wkvb + (size_t)1024 * HID, 1024 * HID / 4);
  cvt_bf16<<<2048, 256, 0, stream>>>(Wo, wob, HID * HID / 4);
  rope_table<<<SEQ * 64 / 256, 256, 0, stream>>>(pos, tab);

  // fused QKV projection: C[2048][6144] = hs * [Wq;Wk;Wv]^T, split epilogue (Q | K | V^T)
  gemm256<3><<<192, 512, 0, stream>>>(hsb, wqb, Qb, Kb, Vtb, nullptr, nullptr, HID);

  rope_apply<<<(SEQ * NH * 64 + SEQ * NKV * 64) / 256, 256, 0, stream>>>(Qb, Kb, tab);

  attn<<<dim3(32, 32), 256, 0, stream>>>(Qb, Kb, Vtb, Ab);

  // o_proj + residual
  gemm256<1><<<128, 512, 0, stream>>>(Ab, wob, nullptr, nullptr, nullptr, out, res, HID);
}

// Round 5
// 520.653 us; speedup vs baseline: 1.9004x; 1.2023x over previous
//
#include <hip/hip_runtime.h>

#define SEQ 2048
#define HID 4096
#define NH 32
#define NKV 8
#define HD 128

typedef __attribute__((ext_vector_type(8))) short short8;
typedef __attribute__((ext_vector_type(4))) float f32x4;

#define CFENCE asm volatile("" ::: "memory")

static __device__ __forceinline__ unsigned short f2bf(float f) {
  union { float f; unsigned u; } v; v.f = f;
  return (unsigned short)((v.u + 0x7fffu + ((v.u >> 16) & 1u)) >> 16);
}
static __device__ __forceinline__ float bf2f(unsigned short h) {
  union { unsigned u; float f; } v; v.u = ((unsigned)h) << 16;
  return v.f;
}

// ---------------- fused fp32 -> bf16 conversion for all 5 tensors ----------------
__global__ void cvt_all(const float* __restrict__ hs, const float* __restrict__ wq,
                        const float* __restrict__ wk, const float* __restrict__ wv,
                        const float* __restrict__ wo,
                        unsigned short* __restrict__ hsb, unsigned short* __restrict__ wqb,
                        unsigned short* __restrict__ wkvb, unsigned short* __restrict__ wob) {
  // segment sizes in float4 units
  const int S0 = 2097152;            // hs  (2048*4096/4)
  const int S1 = S0 + 4194304;       // Wq  (4096*4096/4)
  const int S2 = S1 + 1048576;       // Wk  (1024*4096/4)
  const int S3 = S2 + 1048576;       // Wv
  const int S4 = S3 + 4194304;       // Wo
  int i = blockIdx.x * blockDim.x + threadIdx.x;
  int st = gridDim.x * blockDim.x;
  for (; i < S4; i += st) {
    const float4* src; ushort4* dst; int off;
    if (i < S0)      { src = (const float4*)hs; dst = (ushort4*)hsb;  off = i; }
    else if (i < S1) { src = (const float4*)wq; dst = (ushort4*)wqb;  off = i - S0; }
    else if (i < S2) { src = (const float4*)wk; dst = (ushort4*)wkvb; off = i - S1; }
    else if (i < S3) { src = (const float4*)wv; dst = (ushort4*)wkvb + 1048576; off = i - S2; }
    else             { src = (const float4*)wo; dst = (ushort4*)wob;  off = i - S3; }
    float4 v = src[off];
    ushort4 o;
    o.x = f2bf(v.x); o.y = f2bf(v.y); o.z = f2bf(v.z); o.w = f2bf(v.w);
    dst[off] = o;
  }
}

// ---------------- RoPE cos/sin table ----------------
__global__ void rope_table(const int* __restrict__ pos, float* __restrict__ tab) {
  int t = blockIdx.x * blockDim.x + threadIdx.x;
  if (t >= SEQ * 64) return;
  int s = t >> 6, i = t & 63;
  float inv = powf(10000.0f, -(float)i / 64.0f);
  float ang = (float)pos[s] * inv;
  tab[s * 128 + i] = cosf(ang);
  tab[s * 128 + 64 + i] = sinf(ang);
}

// ---------------- RoPE apply, in place on bf16 Q [2048][4096] and K [2048][1024] ----------------
__global__ void rope_apply(unsigned short* __restrict__ Q, unsigned short* __restrict__ K,
                           const float* __restrict__ tab) {
  int t = blockIdx.x * blockDim.x + threadIdx.x;
  const int QP = SEQ * NH * 64, KP = SEQ * NKV * 64;
  unsigned short* p;
  int s, i;
  if (t < QP) {
    s = t / (NH * 64); int r = t % (NH * 64);
    p = Q + (long)s * HID + (r >> 6) * HD; i = r & 63;
  } else if (t < QP + KP) {
    int u = t - QP;
    s = u / (NKV * 64); int r = u % (NKV * 64);
    p = K + (long)s * 1024 + (r >> 6) * HD; i = r & 63;
  } else return;
  float c = tab[s * 128 + i], sn = tab[s * 128 + 64 + i];
  float x1 = bf2f(p[i]), x2 = bf2f(p[i + 64]);
  p[i]      = f2bf(x1 * c - x2 * sn);
  p[i + 64] = f2bf(x2 * c + x1 * sn);
}

// ---------------- async global->LDS, 16B ----------------
static __device__ __forceinline__ void gl16(const unsigned short* g, unsigned short* l) {
  __builtin_amdgcn_global_load_lds((const __attribute__((address_space(1))) unsigned int*)g,
                                   (__attribute__((address_space(3))) unsigned int*)l, 16, 0, 0);
}

// Stage one 128x64 bf16 tile (16KB) with pre-swizzled global source:
// LDS[row*64 + jc*8] = G[row][(jc ^ (row&7))*8]  (involution). 512 thr x 2 chunks.
static __device__ __forceinline__ void stage128(const unsigned short* __restrict__ gsrc,
                                                unsigned short* __restrict__ dst, int K, int t) {
#pragma unroll
  for (int p = 0; p < 2; p++) {
    int chunk = p * 512 + t;
    int row = chunk >> 3, j = chunk & 7;
    gl16(gsrc + (size_t)row * K + ((j ^ (row & 7)) << 3), dst + chunk * 8);
  }
}

// ======== 128xBN 4-phase BT-GEMM: C[M,N] = A[M,K] * B[N,K]^T ========
// 512 thr = 8 waves (2M x 4N); per-wave C = 64 x BN/4; BK=64; double-buffered LDS.
// Grid must be 16x16=256 blocks (M=2048, N=16*BN). EPI 1: fp32+residual; EPI 3: QKV split.
template <int BN, int EPI>
__global__ __launch_bounds__(512, 2)
void gemm8p(const unsigned short* __restrict__ A, const unsigned short* __restrict__ B,
            unsigned short* __restrict__ Qo, unsigned short* __restrict__ Ko,
            unsigned short* __restrict__ Vt, float* __restrict__ Cf,
            const float* __restrict__ Res, int K) {
  constexpr int NF   = BN / 64;        // n-frags per wave (4 or 6)
  constexpr int NH2  = NF / 2;
  constexpr int NBG  = BN / 128;       // B stage groups (2 or 3)
  constexpr int BUFE = 8192 + BN * 64; // elems per buffer (A 16KB + B BN*128B)
  __shared__ unsigned short smem[2 * BUFE];

  // XCD-aware bijective mapping over the 16x16 tile grid: XCD owns a 4(bm) x 8(bn) region.
  const int fid = blockIdx.x;
  const int xcd = fid & 7, idx = fid >> 3;
  const int bm = (xcd & 3) * 4 + (idx & 3);
  const int bn = (xcd >> 2) * 8 + (idx >> 2);

  const int t = threadIdx.x, lane = t & 63, w = t >> 6, g = lane >> 4, l15 = lane & 15;
  const int wm = w >> 2, wn = w & 3;

  const unsigned short* Abase = A + (size_t)(bm * 128) * K;
  const unsigned short* Bbase = B + (size_t)(bn * BN) * K;

  // prologue: stage K-tile 0 into buffer 0, full drain
  stage128(Abase, smem, K, t);
#pragma unroll
  for (int gi = 0; gi < NBG; gi++)
    stage128(Bbase + (size_t)(gi * 128) * K, smem + 8192 + gi * 8192, K, t);
  asm volatile("s_waitcnt vmcnt(0)" ::: "memory");
  __syncthreads();

  f32x4 acc[4][NF] = {};
  const int NT = K >> 6;

  // LDS read helpers (swizzled)
  const int arow[4] = { wm * 64 + 0 * 16 + l15, wm * 64 + 1 * 16 + l15,
                        wm * 64 + 2 * 16 + l15, wm * 64 + 3 * 16 + l15 };

  for (int kt = 0; kt < NT; kt++) {
    const unsigned short* buf = smem + (kt & 1) * BUFE;
    unsigned short* nbuf = smem + ((kt & 1) ^ 1) * BUFE;
    const size_t knext = (size_t)(kt + 1) * 64;
    const bool pf = (kt + 1 < NT);
    short8 a[4], b[NH2];

    // ---------- phase 0: ks=0, n-half 0 ----------
#pragma unroll
    for (int mf = 0; mf < 4; mf++)
      a[mf] = *reinterpret_cast<const short8*>(buf + arow[mf] * 64 + ((g * 8) ^ ((arow[mf] & 7) << 3)));
#pragma unroll
    for (int i = 0; i < NH2; i++) {
      const int rb = wn * (BN / 4) + i * 16 + l15;
      b[i] = *reinterpret_cast<const short8*>(buf + 8192 + rb * 64 + ((g * 8) ^ ((rb & 7) << 3)));
    }
    if (pf) {
      stage128(Abase + knext, nbuf, K, t);
      stage128(Bbase + knext, nbuf + 8192, K, t);
    }
    CFENCE; __builtin_amdgcn_s_barrier(); CFENCE;
    __builtin_amdgcn_s_setprio(1);
#pragma unroll
    for (int mf = 0; mf < 4; mf++)
#pragma unroll
      for (int i = 0; i < NH2; i++)
        acc[mf][i] = __builtin_amdgcn_mfma_f32_16x16x32_bf16(a[mf], b[i], acc[mf][i], 0, 0, 0);
    __builtin_amdgcn_s_setprio(0);
    CFENCE; __builtin_amdgcn_s_barrier(); CFENCE;

    // ---------- phase 1: ks=0, n-half 1 ----------
#pragma unroll
    for (int i = 0; i < NH2; i++) {
      const int rb = wn * (BN / 4) + (NH2 + i) * 16 + l15;
      b[i] = *reinterpret_cast<const short8*>(buf + 8192 + rb * 64 + ((g * 8) ^ ((rb & 7) << 3)));
    }
    if (pf) stage128(Bbase + (size_t)128 * K + knext, nbuf + 16384, K, t);
    CFENCE; __builtin_amdgcn_s_barrier(); CFENCE;
    __builtin_amdgcn_s_setprio(1);
#pragma unroll
    for (int mf = 0; mf < 4; mf++)
#pragma unroll
      for (int i = 0; i < NH2; i++)
        acc[mf][NH2 + i] = __builtin_amdgcn_mfma_f32_16x16x32_bf16(a[mf], b[i], acc[mf][NH2 + i], 0, 0, 0);
    __builtin_amdgcn_s_setprio(0);
    CFENCE; __builtin_amdgcn_s_barrier(); CFENCE;

    // ---------- phase 2: ks=1, n-half 0 ----------
#pragma unroll
    for (int mf = 0; mf < 4; mf++)
      a[mf] = *reinterpret_cast<const short8*>(buf + arow[mf] * 64 + ((32 + g * 8) ^ ((arow[mf] & 7) << 3)));
#pragma unroll
    for (int i = 0; i < NH2; i++) {
      const int rb = wn * (BN / 4) + i * 16 + l15;
      b[i] = *reinterpret_cast<const short8*>(buf + 8192 + rb * 64 + ((32 + g * 8) ^ ((rb & 7) << 3)));
    }
    if (pf && NBG == 3) stage128(Bbase + (size_t)256 * K + knext, nbuf + 24576, K, t);
    CFENCE; __builtin_amdgcn_s_barrier(); CFENCE;
    __builtin_amdgcn_s_setprio(1);
#pragma unroll
    for (int mf = 0; mf < 4; mf++)
#pragma unroll
      for (int i = 0; i < NH2; i++)
        acc[mf][i] = __builtin_amdgcn_mfma_f32_16x16x32_bf16(a[mf], b[i], acc[mf][i], 0, 0, 0);
    __builtin_amdgcn_s_setprio(0);
    CFENCE; __builtin_amdgcn_s_barrier(); CFENCE;

    // ---------- phase 3: ks=1, n-half 1 ----------
#pragma unroll
    for (int i = 0; i < NH2; i++) {
      const int rb = wn * (BN / 4) + (NH2 + i) * 16 + l15;
      b[i] = *reinterpret_cast<const short8*>(buf + 8192 + rb * 64 + ((32 + g * 8) ^ ((rb & 7) << 3)));
    }
    CFENCE; __builtin_amdgcn_s_barrier(); CFENCE;
    __builtin_amdgcn_s_setprio(1);
#pragma unroll
    for (int mf = 0; mf < 4; mf++)
#pragma unroll
      for (int i = 0; i < NH2; i++)
        acc[mf][NH2 + i] = __builtin_amdgcn_mfma_f32_16x16x32_bf16(a[mf], b[i], acc[mf][NH2 + i], 0, 0, 0);
    __builtin_amdgcn_s_setprio(0);
    if (pf) asm volatile("s_waitcnt vmcnt(0)" ::: "memory");  // next tile staged; max distance from issue
    CFENCE; __builtin_amdgcn_s_barrier(); CFENCE;
  }

  // ---- epilogue ----
  const int r0 = bm * 128 + wm * 64 + g * 4;
  const int c0 = bn * BN + wn * (BN / 4) + l15;
#pragma unroll
  for (int mf = 0; mf < 4; mf++)
#pragma unroll
    for (int nf = 0; nf < NF; nf++) {
      const int row = r0 + mf * 16;
      const int col = c0 + nf * 16;
      if (EPI == 1) {
#pragma unroll
        for (int j = 0; j < 4; j++) {
          size_t idx = (size_t)(row + j) * 4096 + col;
          Cf[idx] = acc[mf][nf][j] + Res[idx];
        }
      } else {
        if (col < 4096) {
#pragma unroll
          for (int j = 0; j < 4; j++)
            Qo[(size_t)(row + j) * 4096 + col] = f2bf(acc[mf][nf][j]);
        } else if (col < 5120) {
#pragma unroll
          for (int j = 0; j < 4; j++)
            Ko[(size_t)(row + j) * 1024 + (col - 4096)] = f2bf(acc[mf][nf][j]);
        } else {
          const int c = col - 5120;
          ushort4 pk;
          pk.x = f2bf(acc[mf][nf][0]); pk.y = f2bf(acc[mf][nf][1]);
          pk.z = f2bf(acc[mf][nf][2]); pk.w = f2bf(acc[mf][nf][3]);
          *reinterpret_cast<ushort4*>(
              Vt + ((size_t)((c >> 7) * 128 + (c & 127))) * 2048 + row) = pk;
        }
      }
    }
}

// ---------------- Flash attention (causal, GQA 4:1) ----------------
// grid: (32 heads, 32 q-blocks); block 256 = 4 waves x 16 q-rows. KVBLK=64.
// K global [2048][1024] (head-major cols), V^T global [8][128][2048].
__global__ __launch_bounds__(256)
void attn(const unsigned short* __restrict__ Q, const unsigned short* __restrict__ Kg,
          const unsigned short* __restrict__ Vg, unsigned short* __restrict__ O) {
  const int h = blockIdx.x, qb = 31 - blockIdx.y, kvh = h >> 2;
  __shared__ unsigned short Kl[64 * 128];   // swizzled rows of 256B
  __shared__ unsigned short Vl[128 * 64];   // V^T tile, swizzled rows of 128B
  __shared__ unsigned short Pl[4][16 * 72]; // per-wave P buffer
  const int t = threadIdx.x, lane = t & 63, w = t >> 6, g = lane >> 4;

  short8 qf[4];
  {
    const int qrow = qb * 64 + w * 16 + (lane & 15);
    const unsigned short* qp = Q + (size_t)qrow * HID + h * HD + g * 8;
#pragma unroll
    for (int kf = 0; kf < 4; kf++) qf[kf] = *reinterpret_cast<const short8*>(qp + kf * 32);
  }

  f32x4 oacc[8] = {};
  float m_run[4], l_run[4];
#pragma unroll
  for (int j = 0; j < 4; j++) { m_run[j] = -3e38f; l_run[j] = 0.f; }

  const float SCL2E = 0.08838834764831845f * 1.4426950408889634f;
  const int ktiles = qb + 1;
  const int qrow_l = qb * 64 + w * 16 + g * 4;

  const unsigned short* kbase = Kg + kvh * HD;
  const unsigned short* vbase = Vg + (size_t)kvh * 128 * 2048;

  short8 kreg[4], vreg[4];
#define LOADKV(KT)                                                                     \
  {                                                                                    \
    _Pragma("unroll") for (int i = 0; i < 4; i++) {                                    \
      int slot = t + i * 256;                                                          \
      kreg[i] = *reinterpret_cast<const short8*>(                                      \
          kbase + (size_t)((KT) * 64 + (slot >> 4)) * 1024 + (slot & 15) * 8);         \
      vreg[i] = *reinterpret_cast<const short8*>(                                      \
          vbase + (size_t)(slot >> 3) * 2048 + (KT) * 64 + (slot & 7) * 8);            \
    }                                                                                  \
  }

  LOADKV(0);

  for (int kt = 0; kt < ktiles; kt++) {
    __syncthreads();  // prior tile's LDS reads complete
#pragma unroll
    for (int i = 0; i < 4; i++) {
      int slot = t + i * 256;
      int kr = slot >> 4, kc = slot & 15;
      *reinterpret_cast<short8*>(Kl + kr * 128 + ((((kc * 16) ^ ((kr & 7) << 4))) >> 1)) = kreg[i];
      int vr = slot >> 3, vc = slot & 7;
      *reinterpret_cast<short8*>(Vl + vr * 64 + ((((vc * 16) ^ ((vr & 7) << 4))) >> 1)) = vreg[i];
    }
    __syncthreads();

    if (kt + 1 < ktiles) LOADKV(kt + 1);  // overlap next-tile global loads with compute

    // ---- S = Q K^T : 16 q x 64 kv per wave ----
    f32x4 sacc[4] = {};
#pragma unroll
    for (int nt = 0; nt < 4; nt++) {
      int row = nt * 16 + (lane & 15);
#pragma unroll
      for (int kf = 0; kf < 4; kf++) {
        short8 kfr = *reinterpret_cast<const short8*>(
            Kl + row * 128 + (((kf * 64 + g * 16) ^ ((row & 7) << 4)) >> 1));
        sacc[nt] = __builtin_amdgcn_mfma_f32_16x16x32_bf16(qf[kf], kfr, sacc[nt], 0, 0, 0);
      }
    }

    // ---- softmax (raw units; scale folded into exp2) ----
    float mt[4];
    if (kt == qb) {  // diagonal tile: causal mask
      const int kc0 = kt * 64 + (lane & 15);
#pragma unroll
      for (int j = 0; j < 4; j++)
#pragma unroll
        for (int nt = 0; nt < 4; nt++)
          if (kc0 + nt * 16 > qrow_l + j) sacc[nt][j] = -3e38f;
    }
#pragma unroll
    for (int j = 0; j < 4; j++)
      mt[j] = fmaxf(fmaxf(sacc[0][j], sacc[1][j]), fmaxf(sacc[2][j], sacc[3][j]));
#pragma unroll
    for (int d = 1; d < 16; d <<= 1)
#pragma unroll
      for (int j = 0; j < 4; j++) mt[j] = fmaxf(mt[j], __shfl_xor(mt[j], d));

    float rs[4], prow[4];
#pragma unroll
    for (int j = 0; j < 4; j++) {
      float mn = fmaxf(m_run[j], mt[j]);
      rs[j] = exp2f((m_run[j] - mn) * SCL2E);
      m_run[j] = mn;
      float mnl = mn * SCL2E;
      float p0 = exp2f(sacc[0][j] * SCL2E - mnl);
      float p1 = exp2f(sacc[1][j] * SCL2E - mnl);
      float p2 = exp2f(sacc[2][j] * SCL2E - mnl);
      float p3 = exp2f(sacc[3][j] * SCL2E - mnl);
      sacc[0][j] = p0; sacc[1][j] = p1; sacc[2][j] = p2; sacc[3][j] = p3;
      prow[j] = (p0 + p1) + (p2 + p3);
    }
#pragma unroll
    for (int d = 1; d < 16; d <<= 1)
#pragma unroll
      for (int j = 0; j < 4; j++) prow[j] += __shfl_xor(prow[j], d);
#pragma unroll
    for (int j = 0; j < 4; j++) l_run[j] = l_run[j] * rs[j] + prow[j];
#pragma unroll
    for (int n8 = 0; n8 < 8; n8++)
#pragma unroll
      for (int j = 0; j < 4; j++) oacc[n8][j] *= rs[j];

    // ---- P -> per-wave LDS -> A-frag ----
    unsigned short* pw = &Pl[w][0];
#pragma unroll
    for (int j = 0; j < 4; j++) {
      int r = g * 4 + j;
#pragma unroll
      for (int nt = 0; nt < 4; nt++)
        pw[r * 72 + nt * 16 + (lane & 15)] = f2bf(sacc[nt][j]);
    }
    short8 pf0 = *reinterpret_cast<const short8*>(pw + (lane & 15) * 72 + g * 8);
    short8 pf1 = *reinterpret_cast<const short8*>(pw + (lane & 15) * 72 + 32 + g * 8);

    // ---- O += P V ----
#pragma unroll
    for (int n8 = 0; n8 < 8; n8++) {
      int row = n8 * 16 + (lane & 15);
      short8 vf0 = *reinterpret_cast<const short8*>(
          Vl + row * 64 + (((g * 16) ^ ((row & 7) << 4)) >> 1));
      oacc[n8] = __builtin_amdgcn_mfma_f32_16x16x32_bf16(pf0, vf0, oacc[n8], 0, 0, 0);
      short8 vf1 = *reinterpret_cast<const short8*>(
          Vl + row * 64 + (((64 + g * 16) ^ ((row & 7) << 4)) >> 1));
      oacc[n8] = __builtin_amdgcn_mfma_f32_16x16x32_bf16(pf1, vf1, oacc[n8], 0, 0, 0);
    }
  }

  float inv[4];
#pragma unroll
  for (int j = 0; j < 4; j++) inv[j] = 1.0f / l_run[j];
  const int orow = qb * 64 + w * 16 + g * 4;
#pragma unroll
  for (int n8 = 0; n8 < 8; n8++)
#pragma unroll
    for (int j = 0; j < 4; j++)
      O[(size_t)(orow + j) * HID + h * HD + n8 * 16 + (lane & 15)] = f2bf(oacc[n8][j] * inv[j]);
#undef LOADKV
}

// ---------------- launch ----------------
extern "C" void kernel_launch(void* const* d_in, const int* in_sizes, int n_in,
                              void* d_out, int out_size, void* d_ws, size_t ws_size,
                              hipStream_t stream) {
  const float* hs  = (const float*)d_in[0];
  const float* res = (const float*)d_in[1];
  const float* Wq  = (const float*)d_in[2];
  const float* Wk  = (const float*)d_in[3];
  const float* Wv  = (const float*)d_in[4];
  const float* Wo  = (const float*)d_in[5];
  const int* pos   = (const int*)d_in[7];
  float* out = (float*)d_out;

  char* w = (char*)d_ws;
  unsigned short* hsb  = (unsigned short*)w; w += (size_t)SEQ * HID * 2;       // 16MB
  unsigned short* wqb  = (unsigned short*)w; w += (size_t)HID * HID * 2;       // 32MB (rows 0-4095 of fused B)
  unsigned short* wkvb = (unsigned short*)w; w += (size_t)2048 * HID * 2;      // 16MB (rows 4096-6143, contiguous)
  unsigned short* wob  = (unsigned short*)w; w += (size_t)HID * HID * 2;       // 32MB
  unsigned short* Qb   = (unsigned short*)w; w += (size_t)SEQ * HID * 2;       // 16MB
  unsigned short* Kb   = (unsigned short*)w; w += (size_t)SEQ * 1024 * 2;      // 4MB
  unsigned short* Vtb  = (unsigned short*)w; w += (size_t)NKV * 128 * SEQ * 2; // 4MB
  unsigned short* Ab   = (unsigned short*)w; w += (size_t)SEQ * HID * 2;       // 16MB
  float* tab           = (float*)w;          w += (size_t)SEQ * 128 * 4;       // 1MB

  cvt_all<<<2048, 256, 0, stream>>>(hs, Wq, Wk, Wv, Wo, hsb, wqb, wkvb, wob);
  rope_table<<<SEQ * 64 / 256, 256, 0, stream>>>(pos, tab);

  // fused QKV projection: C[2048][6144] = hs * [Wq;Wk;Wv]^T, split epilogue (Q | K | V^T)
  gemm8p<384, 3><<<256, 512, 0, stream>>>(hsb, wqb, Qb, Kb, Vtb, nullptr, nullptr, HID);

  rope_apply<<<(SEQ * NH * 64 + SEQ * NKV * 64) / 256, 256, 0, stream>>>(Qb, Kb, tab);

  attn<<<dim3(32, 32), 256, 0, stream>>>(Qb, Kb, Vtb, Ab);

  // o_proj + residual
  gemm8p<256, 1><<<256, 512, 0, stream>>>(Ab, wob, nullptr, nullptr, nullptr, out, res, HID);
}